// Round 1
// baseline (31382.080 us; speedup 1.0000x reference)
//
#include <hip/hip_runtime.h>

// SimpleLSTM: B=256, T=512, I=3, H=512. out[b] = fc(h_T[b]).
// Design: persistent kernel, 256 wgs (16 batch-groups x 16 hidden-blocks).
// wg (bb,hb) owns batch b0..b0+15 x hidden j0..j0+31 (=> 128 of 2048 gate rows).
// Per-step sync only within the 16 wgs of a batch group (atomic counter barrier).
// W_hh is transposed once into ws (k-major, float4-packed over k) for coalesced
// streaming in the dot loop. c stays in registers. h double-buffered in ws.

#define Hh   512
#define Bsz  256
#define Tt   512
#define G4   2048   // 4*H

#define PH   16     // hidden blocks
#define PB   16     // batch blocks
#define JB   32     // hidden per block
#define BBL  16     // batch per block
#define NWG  256
#define NTHR 256

// workspace layout (bytes)
#define WT_OFF     0
#define WT_BYTES   (128 * 2048 * 16)          // float4 Wt4[128][2048] = 4 MiB
#define HBUF_OFF   WT_BYTES
#define HBUF_BYTES (2 * Bsz * Hh * 4)         // 1 MiB
#define BAR_OFF    (HBUF_OFF + HBUF_BYTES)
// ctrl region: 16 barrier counters (stride 16 uints) + 16 flags (stride 16 uints) = 2 KiB
#define CTRL_UINTS 512

__device__ __forceinline__ float sigm(float v)  { return 1.0f / (1.0f + __expf(-v)); }
__device__ __forceinline__ float tanhx(float v) { return 2.0f / (1.0f + __expf(-2.0f * v)) - 1.0f; }

__device__ __forceinline__ void group_barrier(unsigned* bar, int tid, unsigned target) {
  __threadfence();              // release our h writes (all threads)
  __syncthreads();
  if (tid == 0) {
    __hip_atomic_fetch_add(bar, 1u, __ATOMIC_RELEASE, __HIP_MEMORY_SCOPE_AGENT);
    while (__hip_atomic_load(bar, __ATOMIC_ACQUIRE, __HIP_MEMORY_SCOPE_AGENT) < target)
      __builtin_amdgcn_s_sleep(1);
  }
  __syncthreads();
  __threadfence();              // acquire before reading others' h
}

__global__ void init_ws(unsigned* ctrl) {
  ctrl[threadIdx.x] = 0u;       // zero barrier counters + transpose flags
}

__global__ __launch_bounds__(NTHR, 1)
void lstm_kernel(const float* __restrict__ x,   const float* __restrict__ Wih,
                 const float* __restrict__ Whh, const float* __restrict__ bih,
                 const float* __restrict__ bhh, const float* __restrict__ fcw,
                 const float* __restrict__ fcb, float* __restrict__ out,
                 char* __restrict__ ws)
{
  const int tid = threadIdx.x;
  const int wg  = blockIdx.x;
  const int hb  = wg & (PH - 1);
  const int bb  = wg >> 4;
  const int j0  = hb * JB;
  const int b0  = bb * BBL;

  float4*   Wt4   = (float4*)(ws + WT_OFF);
  float*    hbuf0 = (float*)(ws + HBUF_OFF);
  float*    hbuf1 = hbuf0 + Bsz * Hh;
  unsigned* bar   = (unsigned*)(ws + BAR_OFF) + bb * 16;
  unsigned* flag  = (unsigned*)(ws + BAR_OFF) + 256 + hb * 16;

  __shared__ float4 hl4[BBL * 128];      // 16 x 512 floats = 32 KiB
  __shared__ float4 tile[32][33];        // transpose staging, ~16.9 KiB
  __shared__ float  xs[BBL][4];
  __shared__ float  wih_s[128][3];
  __shared__ float  bsum[128];
  __shared__ float  red[256];

  // ---- stage W_ih slice + bias sums (rows q*512 + j0 + j) ----
  if (tid < 128) {
    int row = (tid >> 5) * Hh + j0 + (tid & 31);
    wih_s[tid][0] = Wih[row * 3 + 0];
    wih_s[tid][1] = Wih[row * 3 + 1];
    wih_s[tid][2] = Wih[row * 3 + 2];
    bsum[tid] = bih[row] + bhh[row];
  }

  // ---- one-time transpose of this hidden-block's 128 W_hh rows ----
  // done by batch-group 0 only; other groups wait on per-slice flag.
  if (bb == 0) {
    for (int tr = 0; tr < 4; ++tr) {            // gate quadrant
      int rowbase = tr * Hh + j0;
      for (int tk = 0; tk < 4; ++tk) {          // k4 tile
        __syncthreads();
        #pragma unroll
        for (int m = 0; m < 4; ++m) {
          int id = tid + m * 256;               // 0..1023
          int i = id >> 5, jj = id & 31;
          tile[i][jj] = *(const float4*)&Whh[(size_t)(rowbase + i) * Hh + (tk * 32 + jj) * 4];
        }
        __syncthreads();
        #pragma unroll
        for (int m = 0; m < 4; ++m) {
          int id = tid + m * 256;
          int rr = id & 31, jj = id >> 5;
          Wt4[(size_t)(tk * 32 + jj) * G4 + rowbase + rr] = tile[rr][jj];
        }
      }
    }
    __threadfence();
    __syncthreads();
    if (tid == 0) __hip_atomic_store(flag, 1u, __ATOMIC_RELEASE, __HIP_MEMORY_SCOPE_AGENT);
  } else {
    if (tid == 0) {
      while (__hip_atomic_load(flag, __ATOMIC_ACQUIRE, __HIP_MEMORY_SCOPE_AGENT) == 0u)
        __builtin_amdgcn_s_sleep(2);
    }
    __syncthreads();
    __threadfence();
  }

  // ---- zero-init h_0 (own slice of hbuf0) ----
  for (int i = tid; i < BBL * JB; i += NTHR) {
    int b_ = i >> 5, jj = i & 31;
    hbuf0[(size_t)(b0 + b_) * Hh + j0 + jj] = 0.0f;
  }
  group_barrier(bar, tid, 16u * 1);

  // thread ownership: j = tid&31 (hidden), bA = tid>>5 (0..7), bB = bA+8
  const int j  = tid & 31;
  const int bA = tid >> 5;
  const int bB = bA + 8;
  float cA = 0.0f, cB = 0.0f;

  const float4* wt = Wt4 + (j0 + j);

  int rd = 0;
  for (int t = 0; t < Tt; ++t) {
    const float* hin  = rd ? hbuf1 : hbuf0;
    float*       hout = rd ? hbuf0 : hbuf1;

    // ---- stage h block (16x512 f32) + x_t (16x3) into LDS ----
    __syncthreads();
    {
      const float4* hsrc = (const float4*)(hin + (size_t)b0 * Hh);
      #pragma unroll
      for (int m = 0; m < 8; ++m) {
        int id = tid + m * 256;
        hl4[id] = hsrc[id];
      }
      if (tid < BBL * 3) {
        int b_ = tid / 3, ii = tid - b_ * 3;
        xs[b_][ii] = x[(size_t)(b0 + b_) * (Tt * 3) + t * 3 + ii];
      }
    }
    __syncthreads();

    // ---- init accumulators with x-gate + bias ----
    float accA[4], accB[4];
    #pragma unroll
    for (int q = 0; q < 4; ++q) {
      int lr = q * 32 + j;
      float base = bsum[lr];
      accA[q] = base + xs[bA][0] * wih_s[lr][0] + xs[bA][1] * wih_s[lr][1] + xs[bA][2] * wih_s[lr][2];
      accB[q] = base + xs[bB][0] * wih_s[lr][0] + xs[bB][1] * wih_s[lr][1] + xs[bB][2] * wih_s[lr][2];
    }

    // ---- dot: 4 gate rows x 2 batches, k = 512 ----
    const float4* hA4 = hl4 + bA * 128;
    const float4* hB4 = hl4 + bB * 128;
    #pragma unroll 4
    for (int k4 = 0; k4 < 128; ++k4) {
      float4 w0 = wt[(size_t)k4 * G4 + 0 * Hh];
      float4 w1 = wt[(size_t)k4 * G4 + 1 * Hh];
      float4 w2 = wt[(size_t)k4 * G4 + 2 * Hh];
      float4 w3 = wt[(size_t)k4 * G4 + 3 * Hh];
      float4 ha = hA4[k4];
      float4 hb2 = hB4[k4];
      accA[0] += w0.x*ha.x + w0.y*ha.y + w0.z*ha.z + w0.w*ha.w;
      accA[1] += w1.x*ha.x + w1.y*ha.y + w1.z*ha.z + w1.w*ha.w;
      accA[2] += w2.x*ha.x + w2.y*ha.y + w2.z*ha.z + w2.w*ha.w;
      accA[3] += w3.x*ha.x + w3.y*ha.y + w3.z*ha.z + w3.w*ha.w;
      accB[0] += w0.x*hb2.x + w0.y*hb2.y + w0.z*hb2.z + w0.w*hb2.w;
      accB[1] += w1.x*hb2.x + w1.y*hb2.y + w1.z*hb2.z + w1.w*hb2.w;
      accB[2] += w2.x*hb2.x + w2.y*hb2.y + w2.z*hb2.z + w2.w*hb2.w;
      accB[3] += w3.x*hb2.x + w3.y*hb2.y + w3.z*hb2.z + w3.w*hb2.w;
    }

    // ---- gates -> c,h update; write h slice ----
    {
      float iA = sigm(accA[0]), fA = sigm(accA[1]), gA = tanhx(accA[2]), oA = sigm(accA[3]);
      cA = fA * cA + iA * gA;
      float hAv = oA * tanhx(cA);
      float iB = sigm(accB[0]), fB = sigm(accB[1]), gB = tanhx(accB[2]), oB = sigm(accB[3]);
      cB = fB * cB + iB * gB;
      float hBv = oB * tanhx(cB);
      hout[(size_t)(b0 + bA) * Hh + j0 + j] = hAv;
      hout[(size_t)(b0 + bB) * Hh + j0 + j] = hBv;
    }

    group_barrier(bar, tid, 16u * (t + 2));
    rd ^= 1;
  }

  // ---- epilogue: hb==0 wgs compute out[b0..b0+15] = h_T . fc_w + fc_b ----
  if (hb == 0) {
    const float* hfin = rd ? hbuf1 : hbuf0;
    int b_ = tid >> 4;
    int l  = tid & 15;
    float p = 0.0f;
    for (int jj = l; jj < Hh; jj += 16)
      p += hfin[(size_t)(b0 + b_) * Hh + jj] * fcw[jj];
    red[tid] = p;
    __syncthreads();
    if (l == 0) {
      float s = 0.0f;
      #pragma unroll
      for (int q = 0; q < 16; ++q) s += red[(b_ << 4) + q];
      out[b0 + b_] = s + fcb[0];
    }
  }
}

extern "C" void kernel_launch(void* const* d_in, const int* in_sizes, int n_in,
                              void* d_out, int out_size, void* d_ws, size_t ws_size,
                              hipStream_t stream) {
  const float* x   = (const float*)d_in[0];
  const float* Wih = (const float*)d_in[1];
  const float* Whh = (const float*)d_in[2];
  const float* bih = (const float*)d_in[3];
  const float* bhh = (const float*)d_in[4];
  const float* fcw = (const float*)d_in[5];
  const float* fcb = (const float*)d_in[6];
  float* out = (float*)d_out;
  char*  ws  = (char*)d_ws;

  hipLaunchKernelGGL(init_ws, dim3(1), dim3(CTRL_UINTS), 0, stream,
                     (unsigned*)(ws + BAR_OFF));
  hipLaunchKernelGGL(lstm_kernel, dim3(NWG), dim3(NTHR), 0, stream,
                     x, Wih, Whh, bih, bhh, fcw, fcb, out, ws);
}